// Round 1
// baseline (420.131 us; speedup 1.0000x reference)
//
#include <hip/hip_runtime.h>
#include <hip/hip_bf16.h>
#include <stdint.h>

// Problem constants
static constexpr int Bsz = 1024;
static constexpr int TT  = 256;
static constexpr int FF  = 124;
static constexpr int HH  = 64;
static constexpr int GG  = 256;   // 4*H
static constexpr int KK  = 128;   // F + ADIM
static constexpr int BB  = 16;    // batch rows per block
static constexpr int C_OFF = Bsz * 8;            // 8192
static constexpr int H_OFF = C_OFF + Bsz * HH;   // 73728

typedef __attribute__((ext_vector_type(8))) short bf16x8;
typedef __attribute__((ext_vector_type(4))) float f32x4;

__device__ __forceinline__ uint16_t f2bf(float x) {
  union { float f; uint32_t u; } v; v.f = x;
  return (uint16_t)((v.u + 0x7FFFu + ((v.u >> 16) & 1u)) >> 16);
}
__device__ __forceinline__ float fsig(float x) {
  return 1.0f / (1.0f + __expf(-x));
}
__device__ __forceinline__ float ftanh(float x) {
  float e = __expf(-2.0f * x);
  return (1.0f - e) / (1.0f + e);
}

// B-fragment for mfma_f32_16x16x32_bf16 from a row-major f32 matrix [K][ld]:
// lane holds B[k0 + j][colB], k0 = m*32 + (lane>>4)*8, j=0..7
__device__ __forceinline__ void load_bfrag(bf16x8& frag, const float* __restrict__ Wp,
                                           int m, int kg, int colB, int ld) {
#pragma unroll
  for (int j = 0; j < 8; ++j) {
    int k = m * 32 + kg * 8 + j;
    frag[j] = (short)f2bf(Wp[(size_t)k * ld + colB]);
  }
}

__global__ __launch_bounds__(1024) void actor_fused(
    const float* __restrict__ x,  const float* __restrict__ pa,
    const float* __restrict__ Wx, const float* __restrict__ Wh,
    const float* __restrict__ bg, const float* __restrict__ W1,
    const float* __restrict__ b1, const float* __restrict__ W2,
    const float* __restrict__ b2, const float* __restrict__ W3,
    const float* __restrict__ b3, float* __restrict__ out)
{
  // LDS. xs/h are bf16, XOR-swizzled in 16B chunks: chunk ^= (row&7)
  __shared__ __align__(16) uint16_t xs_lds[2][BB * KK];  // 2 x 4 KB
  __shared__ __align__(16) uint16_t h_lds[BB * HH];      // 2 KB
  __shared__ float gates_lds[BB * 257];                  // 16.4 KB (stride 257 breaks bank aliasing)
  __shared__ float red_lds[2 * BB * 65];                 // 8.3 KB  (W1 partial reduce)
  __shared__ float a_lds[BB * HH];                       // 4 KB    (MLP activations)

  const int tid   = threadIdx.x;
  const int w     = tid >> 6;     // wave 0..15 == batch row for elementwise phase
  const int l     = tid & 63;
  const int row16 = l & 15;       // A-row / B-col / D-col within MFMA tile
  const int kg    = l >> 4;       // 0..3
  const int b0    = blockIdx.x * BB;

  // ---- prologue: persistent B-fragments (Wx: 4 frags K=128, Wh: 2 frags K=64) ----
  const int colB = 16 * w + row16;
  bf16x8 bwx0, bwx1, bwx2, bwx3, bwh0, bwh1;
  load_bfrag(bwx0, Wx, 0, kg, colB, GG);
  load_bfrag(bwx1, Wx, 1, kg, colB, GG);
  load_bfrag(bwx2, Wx, 2, kg, colB, GG);
  load_bfrag(bwx3, Wx, 3, kg, colB, GG);
  load_bfrag(bwh0, Wh, 0, kg, colB, GG);
  load_bfrag(bwh1, Wh, 1, kg, colB, GG);
  const float bias = bg[colB];

  // W1-accumulation role (waves 8..15): kh = K-half, nt = N-tile of the 64 cols
  const int kh = (w - 8) >> 2;
  const int nt = (w - 8) & 3;
  f32x4 wacc = {0.f, 0.f, 0.f, 0.f};

  // init h = 0, c = 0
  h_lds[tid] = 0;  // BB*HH == 1024 == blockDim
  float c = 0.f;

  // xs staging geometry: each thread loads 2 consecutive f32 of row sb
  const int sb = w;                // one row per wave -> coalesced 496B row reads
  const int sf = l * 2;            // 0,2,...,126
  const int st_byte = sb * 256 + ((((sf >> 3) << 4)) ^ ((sb & 7) << 4)) + (sf & 7) * 2;

  // stage t = 0
  {
    float2 v;
    if (sf < FF) v = *reinterpret_cast<const float2*>(x + ((size_t)(b0 + sb) * TT + 0) * FF + sf);
    else         v = *reinterpret_cast<const float2*>(pa + ((size_t)(b0 + sb) * TT + 0) * 4 + (sf - FF));
    uint32_t pk = (uint32_t)f2bf(v.x) | ((uint32_t)f2bf(v.y) << 16);
    *(uint32_t*)((char*)&xs_lds[0][0] + st_byte) = pk;
  }
  __syncthreads();

  const int swz = (row16 & 7) << 4;
  int cur = 0;

  for (int t = 0; t < TT; ++t) {
    // --- prefetch xs(t+1) (issued early; lands during MFMA phase) ---
    const int tp = (t + 1 < TT) ? (t + 1) : (TT - 1);
    float2 pv;
    if (sf < FF) pv = *reinterpret_cast<const float2*>(x + ((size_t)(b0 + sb) * TT + tp) * FF + sf);
    else         pv = *reinterpret_cast<const float2*>(pa + ((size_t)(b0 + sb) * TT + tp) * 4 + (sf - FF));

    // --- W1 B-frag for timestep t-1 (waves 8..15) ---
    bf16x8 bw1;
    if (w >= 8 && t > 0) {
      const size_t r0 = (size_t)(t - 1) * 64 + kh * 32 + kg * 8;
      const int c1 = 16 * nt + row16;
#pragma unroll
      for (int j = 0; j < 8; ++j) bw1[j] = (short)f2bf(W1[(r0 + j) * 64 + c1]);
    }

    // --- A-fragments from LDS (swizzled b128 reads, at the 8-lane/bank-group floor) ---
    const char* xb = (const char*)&xs_lds[cur][0];
    const char* hb = (const char*)&h_lds[0];
    bf16x8 ax0 = *(const bf16x8*)(xb + row16 * 256 + (((0 * 4 + kg) << 4) ^ swz));
    bf16x8 ax1 = *(const bf16x8*)(xb + row16 * 256 + (((1 * 4 + kg) << 4) ^ swz));
    bf16x8 ax2 = *(const bf16x8*)(xb + row16 * 256 + (((2 * 4 + kg) << 4) ^ swz));
    bf16x8 ax3 = *(const bf16x8*)(xb + row16 * 256 + (((3 * 4 + kg) << 4) ^ swz));
    bf16x8 ah0 = *(const bf16x8*)(hb + row16 * 128 + (((0 + kg) << 4) ^ swz));
    bf16x8 ah1 = *(const bf16x8*)(hb + row16 * 128 + (((4 + kg) << 4) ^ swz));

    // --- gate MFMAs: gates = bias + xs*Wx + h*Wh (one 16x16 tile per wave) ---
    f32x4 acc = {bias, bias, bias, bias};
    acc = __builtin_amdgcn_mfma_f32_16x16x32_bf16(ax0, bwx0, acc, 0, 0, 0);
    acc = __builtin_amdgcn_mfma_f32_16x16x32_bf16(ax1, bwx1, acc, 0, 0, 0);
    acc = __builtin_amdgcn_mfma_f32_16x16x32_bf16(ax2, bwx2, acc, 0, 0, 0);
    acc = __builtin_amdgcn_mfma_f32_16x16x32_bf16(ax3, bwx3, acc, 0, 0, 0);
    acc = __builtin_amdgcn_mfma_f32_16x16x32_bf16(ah0, bwh0, acc, 0, 0, 0);
    acc = __builtin_amdgcn_mfma_f32_16x16x32_bf16(ah1, bwh1, acc, 0, 0, 0);
    if (w >= 8 && t > 0) {
      bf16x8 aw = kh ? ah1 : ah0;
      wacc = __builtin_amdgcn_mfma_f32_16x16x32_bf16(aw, bw1, wacc, 0, 0, 0);
    }

    // --- store gate tile: D[r][c], r = kg*4+i, c = l&15 ---
    {
      const int cc = 16 * w + row16;
      const int r0 = kg * 4;
      gates_lds[(r0 + 0) * 257 + cc] = acc[0];
      gates_lds[(r0 + 1) * 257 + cc] = acc[1];
      gates_lds[(r0 + 2) * 257 + cc] = acc[2];
      gates_lds[(r0 + 3) * 257 + cc] = acc[3];
    }

    // --- write prefetched xs(t+1) into the other buffer ---
    {
      uint32_t pk = (uint32_t)f2bf(pv.x) | ((uint32_t)f2bf(pv.y) << 16);
      *(uint32_t*)((char*)&xs_lds[cur ^ 1][0] + st_byte) = pk;
    }

    __syncthreads();

    // --- elementwise LSTM update: thread (b=w, k=l) ---
    {
      const int base = w * 257 + l;
      float gi = gates_lds[base];
      float gf = gates_lds[base + 64];
      float gg = gates_lds[base + 128];
      float go = gates_lds[base + 192];
      float i_ = fsig(gi), f_ = fsig(gf), g_ = ftanh(gg), o_ = fsig(go);
      c = f_ * c + i_ * g_;
      float hh = o_ * ftanh(c);
      const int hbyte = w * 128 + ((((l >> 3) << 4)) ^ ((w & 7) << 4)) + (l & 7) * 2;
      *(uint16_t*)((char*)&h_lds[0] + hbyte) = f2bf(hh);
      if (t == TT - 1) {
        out[C_OFF + (size_t)(b0 + w) * HH + l] = c;
        out[H_OFF + (size_t)(b0 + w) * HH + l] = hh;
      }
    }
    __syncthreads();
    cur ^= 1;
  }

  // ---- final W1 accumulation for t = TT-1 (h_255 is in h_lds) ----
  if (w >= 8) {
    const char* hb = (const char*)&h_lds[0];
    bf16x8 aw = *(const bf16x8*)(hb + row16 * 128 + (((kh * 4 + kg) << 4) ^ swz));
    bf16x8 bw1;
    const size_t r0 = (size_t)(TT - 1) * 64 + kh * 32 + kg * 8;
    const int c1 = 16 * nt + row16;
#pragma unroll
    for (int j = 0; j < 8; ++j) bw1[j] = (short)f2bf(W1[(r0 + j) * 64 + c1]);
    wacc = __builtin_amdgcn_mfma_f32_16x16x32_bf16(aw, bw1, wacc, 0, 0, 0);
    const int rr = kg * 4;
    const int cc = nt * 16 + row16;
    red_lds[(kh * BB + rr + 0) * 65 + cc] = wacc[0];
    red_lds[(kh * BB + rr + 1) * 65 + cc] = wacc[1];
    red_lds[(kh * BB + rr + 2) * 65 + cc] = wacc[2];
    red_lds[(kh * BB + rr + 3) * 65 + cc] = wacc[3];
  }
  __syncthreads();

  // ---- MLP head, thread (b=w, j=l) ----
  {
    float a1 = red_lds[(0 * BB + w) * 65 + l] + red_lds[(1 * BB + w) * 65 + l] + b1[l];
    a_lds[w * 64 + l] = fmaxf(a1, 0.f);
  }
  __syncthreads();
  float acc2 = b2[l];
#pragma unroll 4
  for (int k = 0; k < 64; ++k) acc2 += a_lds[w * 64 + k] * W2[(size_t)k * 64 + l];
  acc2 = fmaxf(acc2, 0.f);
  __syncthreads();
  a_lds[w * 64 + l] = acc2;
  __syncthreads();
  if (l < 8) {
    float acc3 = b3[l];
#pragma unroll 4
    for (int k = 0; k < 64; ++k) acc3 += a_lds[w * 64 + k] * W3[(size_t)k * 8 + l];
    out[(size_t)(b0 + w) * 8 + l] = acc3;
  }
}

extern "C" void kernel_launch(void* const* d_in, const int* in_sizes, int n_in,
                              void* d_out, int out_size, void* d_ws, size_t ws_size,
                              hipStream_t stream) {
  const float* x  = (const float*)d_in[0];
  const float* pa = (const float*)d_in[1];
  const float* Wx = (const float*)d_in[2];
  const float* Wh = (const float*)d_in[3];
  const float* bg = (const float*)d_in[4];
  const float* W1 = (const float*)d_in[5];
  const float* b1 = (const float*)d_in[6];
  const float* W2 = (const float*)d_in[7];
  const float* b2 = (const float*)d_in[8];
  const float* W3 = (const float*)d_in[9];
  const float* b3 = (const float*)d_in[10];
  (void)in_sizes; (void)n_in; (void)out_size; (void)d_ws; (void)ws_size;
  actor_fused<<<dim3(Bsz / BB), dim3(1024), 0, stream>>>(
      x, pa, Wx, Wh, bg, W1, b1, W2, b2, W3, b3, (float*)d_out);
}

// Round 2
// 384.220 us; speedup vs baseline: 1.0935x; 1.0935x over previous
//
#include <hip/hip_runtime.h>
#include <hip/hip_bf16.h>
#include <stdint.h>

static constexpr int Bsz = 1024;
static constexpr int TT  = 256;
static constexpr int FF  = 124;
static constexpr int HH  = 64;
static constexpr int GG  = 256;   // 4*H
static constexpr int BB  = 16;    // batch rows per block
static constexpr int C_OFF = Bsz * 8;
static constexpr int H_OFF = C_OFF + Bsz * HH;

typedef __attribute__((ext_vector_type(8))) short bf16x8;
typedef __attribute__((ext_vector_type(4))) float f32x4;

#define MFMA16 __builtin_amdgcn_mfma_f32_16x16x32_bf16

__device__ __forceinline__ uint16_t f2bf(float x) {
  union { float f; uint32_t u; } v; v.f = x;
  return (uint16_t)((v.u + 0x7FFFu + ((v.u >> 16) & 1u)) >> 16);
}
// sigmoid/tanh via native v_exp_f32 + v_rcp_f32 (2 trans each, no div sequence)
__device__ __forceinline__ float fsig(float x) {
  return __builtin_amdgcn_rcpf(1.0f + __builtin_amdgcn_exp2f(-1.4426950408889634f * x));
}
__device__ __forceinline__ float ftanh(float x) {
  float e = __builtin_amdgcn_exp2f(-2.8853900817779268f * x);
  return (1.0f - e) * __builtin_amdgcn_rcpf(1.0f + e);
}

__global__ __launch_bounds__(256, 1) void actor_fused(
    const float* __restrict__ x,  const float* __restrict__ pa,
    const float* __restrict__ Wx, const float* __restrict__ Wh,
    const float* __restrict__ bg, const float* __restrict__ W1,
    const float* __restrict__ b1, const float* __restrict__ W2,
    const float* __restrict__ b2, const float* __restrict__ W3,
    const float* __restrict__ b3, float* __restrict__ out)
{
  // bf16 tiles, XOR-swizzled in 16B chunks (chunk ^= (row&7))
  __shared__ __align__(16) uint16_t xs_lds[2][BB * 128];  // 2 x 4 KB
  __shared__ __align__(16) uint16_t h_lds[2][BB * HH];    // 2 x 2 KB
  __shared__ float w2_lds[64 * 64];                       // 16 KB
  __shared__ float mlp_a[BB * 65];                        // 4.2 KB
  __shared__ float mlp_b[BB * 65];                        // 4.2 KB

  const int tid   = threadIdx.x;
  const int w     = tid >> 6;     // wave 0..3 == hidden k-slice [16w,16w+16)
  const int l     = tid & 63;
  const int row16 = l & 15;
  const int kg    = l >> 4;       // 0..3
  const int b0    = blockIdx.x * BB;
  const int swz   = (row16 & 7) << 4;

  // ---- persistent B-fragments: Wx (4 tiles x 4 K-frags), Wh (4 tiles x 2) ----
  bf16x8 bwx[4][4], bwh[4][2];
  float bias4[4];
#pragma unroll
  for (int g = 0; g < 4; ++g) {
    const int col = g * 64 + w * 16 + row16;
    bias4[g] = bg[col];
#pragma unroll
    for (int kf = 0; kf < 4; ++kf)
#pragma unroll
      for (int j = 0; j < 8; ++j)
        bwx[g][kf][j] = (short)f2bf(Wx[(size_t)(kf * 32 + kg * 8 + j) * GG + col]);
#pragma unroll
    for (int kf = 0; kf < 2; ++kf)
#pragma unroll
      for (int j = 0; j < 8; ++j)
        bwh[g][kf][j] = (short)f2bf(Wh[(size_t)(kf * 32 + kg * 8 + j) * GG + col]);
  }

  // stage W2 into LDS (one-time)
  for (int i = tid; i < 64 * 64; i += 256) w2_lds[i] = W2[i];

  // zero h_lds[0] (h_{-1} = 0): 1024 u16 = 256 u64
  reinterpret_cast<uint64_t*>(&h_lds[0][0])[tid] = 0ull;

  // ---- xs staging geometry: thread -> (row, 8-float chunk) ----
  const int srow = tid >> 4;   // 0..15
  const int li   = tid & 15;   // chunk index
  const int st_byte = srow * 256 + ((li << 4) ^ ((srow & 7) << 4));

  // stage xs(0) directly
  {
    const size_t base = (size_t)(b0 + srow) * TT + 0;
    float4 fa, fb;
    if (li < 15) { fa = *(const float4*)(x + base * FF + li * 8);
                   fb = *(const float4*)(x + base * FF + li * 8 + 4); }
    else         { fa = *(const float4*)(x + base * FF + 120);
                   fb = *(const float4*)(pa + base * 4); }
    uint4 pk;
    pk.x = (uint32_t)f2bf(fa.x) | ((uint32_t)f2bf(fa.y) << 16);
    pk.y = (uint32_t)f2bf(fa.z) | ((uint32_t)f2bf(fa.w) << 16);
    pk.z = (uint32_t)f2bf(fb.x) | ((uint32_t)f2bf(fb.y) << 16);
    pk.w = (uint32_t)f2bf(fb.z) | ((uint32_t)f2bf(fb.w) << 16);
    *(uint4*)((char*)&xs_lds[0][0] + st_byte) = pk;
  }
  // prefetch xs(1) into regs (distance-2 pipeline)
  float4 pfa, pfb;
  {
    const size_t base = (size_t)(b0 + srow) * TT + 1;
    if (li < 15) { pfa = *(const float4*)(x + base * FF + li * 8);
                   pfb = *(const float4*)(x + base * FF + li * 8 + 4); }
    else         { pfa = *(const float4*)(x + base * FF + 120);
                   pfb = *(const float4*)(pa + base * 4); }
  }
  __syncthreads();

  f32x4 cacc = {0.f, 0.f, 0.f, 0.f};   // c for rows kg*4+jj, col w*16+row16
  f32x4 wacc = {0.f, 0.f, 0.f, 0.f};   // W1 accumulator (a1 cols w*16+row16)
  int cur = 0;

  for (int t = 0; t < TT; ++t) {
    // 1. write prefetched xs(t+1) (loaded last iteration -> latency covered)
    {
      uint4 pk;
      pk.x = (uint32_t)f2bf(pfa.x) | ((uint32_t)f2bf(pfa.y) << 16);
      pk.y = (uint32_t)f2bf(pfa.z) | ((uint32_t)f2bf(pfa.w) << 16);
      pk.z = (uint32_t)f2bf(pfb.x) | ((uint32_t)f2bf(pfb.y) << 16);
      pk.w = (uint32_t)f2bf(pfb.z) | ((uint32_t)f2bf(pfb.w) << 16);
      *(uint4*)((char*)&xs_lds[cur ^ 1][0] + st_byte) = pk;
    }
    // 2. issue loads for xs(t+2)
    {
      const int tp = (t + 2 < TT) ? (t + 2) : (TT - 1);
      const size_t base = (size_t)(b0 + srow) * TT + tp;
      if (li < 15) { pfa = *(const float4*)(x + base * FF + li * 8);
                     pfb = *(const float4*)(x + base * FF + li * 8 + 4); }
      else         { pfa = *(const float4*)(x + base * FF + 120);
                     pfb = *(const float4*)(pa + base * 4); }
    }
    // 3. W1 B-frags for flat rows (t-1)*64 .. (cols w*16+row16)
    bf16x8 bw1a, bw1b;
    if (t > 0) {
      const size_t r0 = (size_t)(t - 1) * 64 + kg * 8;
      const int c1w = w * 16 + row16;
#pragma unroll
      for (int j = 0; j < 8; ++j) {
        bw1a[j] = (short)f2bf(W1[(r0 + j) * 64 + c1w]);
        bw1b[j] = (short)f2bf(W1[(r0 + 32 + j) * 64 + c1w]);
      }
    }
    // 4. A-fragments from LDS
    const char* xb = (const char*)&xs_lds[cur][0];
    const char* hb = (const char*)&h_lds[cur][0];
    bf16x8 ax0 = *(const bf16x8*)(xb + row16 * 256 + (((0 * 4 + kg) << 4) ^ swz));
    bf16x8 ax1 = *(const bf16x8*)(xb + row16 * 256 + (((1 * 4 + kg) << 4) ^ swz));
    bf16x8 ax2 = *(const bf16x8*)(xb + row16 * 256 + (((2 * 4 + kg) << 4) ^ swz));
    bf16x8 ax3 = *(const bf16x8*)(xb + row16 * 256 + (((3 * 4 + kg) << 4) ^ swz));
    bf16x8 ah0 = *(const bf16x8*)(hb + row16 * 128 + (((0 + kg) << 4) ^ swz));
    bf16x8 ah1 = *(const bf16x8*)(hb + row16 * 128 + (((4 + kg) << 4) ^ swz));

    // 5. gate MFMAs (i,f,g,o tiles for this wave's k-slice)
    f32x4 g0 = {bias4[0], bias4[0], bias4[0], bias4[0]};
    f32x4 g1 = {bias4[1], bias4[1], bias4[1], bias4[1]};
    f32x4 g2 = {bias4[2], bias4[2], bias4[2], bias4[2]};
    f32x4 g3 = {bias4[3], bias4[3], bias4[3], bias4[3]};
    g0 = MFMA16(ax0, bwx[0][0], g0, 0, 0, 0);
    g1 = MFMA16(ax0, bwx[1][0], g1, 0, 0, 0);
    g2 = MFMA16(ax0, bwx[2][0], g2, 0, 0, 0);
    g3 = MFMA16(ax0, bwx[3][0], g3, 0, 0, 0);
    g0 = MFMA16(ax1, bwx[0][1], g0, 0, 0, 0);
    g1 = MFMA16(ax1, bwx[1][1], g1, 0, 0, 0);
    g2 = MFMA16(ax1, bwx[2][1], g2, 0, 0, 0);
    g3 = MFMA16(ax1, bwx[3][1], g3, 0, 0, 0);
    g0 = MFMA16(ax2, bwx[0][2], g0, 0, 0, 0);
    g1 = MFMA16(ax2, bwx[1][2], g1, 0, 0, 0);
    g2 = MFMA16(ax2, bwx[2][2], g2, 0, 0, 0);
    g3 = MFMA16(ax2, bwx[3][2], g3, 0, 0, 0);
    g0 = MFMA16(ax3, bwx[0][3], g0, 0, 0, 0);
    g1 = MFMA16(ax3, bwx[1][3], g1, 0, 0, 0);
    g2 = MFMA16(ax3, bwx[2][3], g2, 0, 0, 0);
    g3 = MFMA16(ax3, bwx[3][3], g3, 0, 0, 0);
    g0 = MFMA16(ah0, bwh[0][0], g0, 0, 0, 0);
    g1 = MFMA16(ah0, bwh[1][0], g1, 0, 0, 0);
    g2 = MFMA16(ah0, bwh[2][0], g2, 0, 0, 0);
    g3 = MFMA16(ah0, bwh[3][0], g3, 0, 0, 0);
    g0 = MFMA16(ah1, bwh[0][1], g0, 0, 0, 0);
    g1 = MFMA16(ah1, bwh[1][1], g1, 0, 0, 0);
    g2 = MFMA16(ah1, bwh[2][1], g2, 0, 0, 0);
    g3 = MFMA16(ah1, bwh[3][1], g3, 0, 0, 0);
    if (t > 0) {
      wacc = MFMA16(ah0, bw1a, wacc, 0, 0, 0);
      wacc = MFMA16(ah1, bw1b, wacc, 0, 0, 0);
    }

    // 6. lane-local LSTM update; write h_t (bf16, swizzled) to other buffer
    const int kcol = w * 16 + row16;
#pragma unroll
    for (int jj = 0; jj < 4; ++jj) {
      float i_ = fsig(g0[jj]);
      float f_ = fsig(g1[jj]);
      float gv = ftanh(g2[jj]);
      float o_ = fsig(g3[jj]);
      float cn = f_ * cacc[jj] + i_ * gv;
      cacc[jj] = cn;
      float hv = o_ * ftanh(cn);
      const int row = kg * 4 + jj;
      *(uint16_t*)((char*)&h_lds[cur ^ 1][0] + row * 128 +
                   (((kcol >> 3) << 4) ^ ((row & 7) << 4)) + (kcol & 7) * 2) = f2bf(hv);
      if (t == TT - 1) {
        out[C_OFF + (size_t)(b0 + row) * HH + kcol] = cn;
        out[H_OFF + (size_t)(b0 + row) * HH + kcol] = hv;
      }
    }
    __syncthreads();
    cur ^= 1;
  }

  // ---- W1 tail: accumulate h_255 (now in h_lds[cur]) ----
  {
    const char* hb = (const char*)&h_lds[cur][0];
    bf16x8 at0 = *(const bf16x8*)(hb + row16 * 128 + (((0 + kg) << 4) ^ swz));
    bf16x8 at1 = *(const bf16x8*)(hb + row16 * 128 + (((4 + kg) << 4) ^ swz));
    bf16x8 bw1a, bw1b;
    const size_t r0 = (size_t)(TT - 1) * 64 + kg * 8;
    const int c1w = w * 16 + row16;
#pragma unroll
    for (int j = 0; j < 8; ++j) {
      bw1a[j] = (short)f2bf(W1[(r0 + j) * 64 + c1w]);
      bw1b[j] = (short)f2bf(W1[(r0 + 32 + j) * 64 + c1w]);
    }
    wacc = MFMA16(at0, bw1a, wacc, 0, 0, 0);
    wacc = MFMA16(at1, bw1b, wacc, 0, 0, 0);
  }

  // ---- MLP head ----
  {
    const int kcol = w * 16 + row16;
    const float bv = b1[kcol];
#pragma unroll
    for (int jj = 0; jj < 4; ++jj)
      mlp_a[(kg * 4 + jj) * 65 + kcol] = fmaxf(wacc[jj] + bv, 0.f);
  }
  __syncthreads();
  {
    const int b = tid >> 4, j0 = tid & 15;
    float s0 = b2[j0], s1 = b2[j0 + 16], s2 = b2[j0 + 32], s3 = b2[j0 + 48];
#pragma unroll 8
    for (int k = 0; k < 64; ++k) {
      const float av = mlp_a[b * 65 + k];
      s0 += av * w2_lds[k * 64 + j0];
      s1 += av * w2_lds[k * 64 + j0 + 16];
      s2 += av * w2_lds[k * 64 + j0 + 32];
      s3 += av * w2_lds[k * 64 + j0 + 48];
    }
    mlp_b[b * 65 + j0]      = fmaxf(s0, 0.f);
    mlp_b[b * 65 + j0 + 16] = fmaxf(s1, 0.f);
    mlp_b[b * 65 + j0 + 32] = fmaxf(s2, 0.f);
    mlp_b[b * 65 + j0 + 48] = fmaxf(s3, 0.f);
  }
  __syncthreads();
  if (tid < 128) {
    const int b = tid >> 3, jj = tid & 7;
    float s = b3[jj];
#pragma unroll 8
    for (int k = 0; k < 64; ++k) s += mlp_b[b * 65 + k] * W3[(size_t)k * 8 + jj];
    out[(size_t)(b0 + b) * 8 + jj] = s;
  }
}

extern "C" void kernel_launch(void* const* d_in, const int* in_sizes, int n_in,
                              void* d_out, int out_size, void* d_ws, size_t ws_size,
                              hipStream_t stream) {
  const float* x  = (const float*)d_in[0];
  const float* pa = (const float*)d_in[1];
  const float* Wx = (const float*)d_in[2];
  const float* Wh = (const float*)d_in[3];
  const float* bg = (const float*)d_in[4];
  const float* W1 = (const float*)d_in[5];
  const float* b1 = (const float*)d_in[6];
  const float* W2 = (const float*)d_in[7];
  const float* b2 = (const float*)d_in[8];
  const float* W3 = (const float*)d_in[9];
  const float* b3 = (const float*)d_in[10];
  (void)in_sizes; (void)n_in; (void)out_size; (void)d_ws; (void)ws_size;
  actor_fused<<<dim3(Bsz / BB), dim3(256), 0, stream>>>(
      x, pa, Wx, Wh, bg, W1, b1, W2, b2, W3, b3, (float*)d_out);
}